// Round 5
// baseline (197.721 us; speedup 1.0000x reference)
//
#include <hip/hip_runtime.h>
#include <hip/hip_bf16.h>

#define N_TOK 8192
#define DIN   1024
#define DOUT  1024
#define NE    8
#define KTOT  (NE * DIN)          // 8192
#define BM    256
#define BN    128
#define NKH   (KTOT / 32)         // 256 phases (k=32 each)

typedef __attribute__((ext_vector_type(4))) float f32x4;
typedef __attribute__((ext_vector_type(8))) short short8;
typedef unsigned int u32;

__device__ __forceinline__ ushort f2bf(float f) {
    u32 u = __float_as_uint(f);
    u32 r = (u + 0x7fffu + ((u >> 16) & 1u)) >> 16;   // round-to-nearest-even
    return (ushort)r;
}

__device__ __forceinline__ void gload_lds16(const void* gp, void* lp) {
    __builtin_amdgcn_global_load_lds(
        (const __attribute__((address_space(1))) u32*)gp,
        (__attribute__((address_space(3))) u32*)lp, 16, 0, 0);
}

#define PH_BAR()  __builtin_amdgcn_s_barrier()
#define LGKM0()   asm volatile("s_waitcnt lgkmcnt(0)" ::: "memory")
#define LGKM8()   asm volatile("s_waitcnt lgkmcnt(8)" ::: "memory")
#define VMCNT3()  asm volatile("s_waitcnt vmcnt(3)" ::: "memory")
#define VMCNT0()  asm volatile("s_waitcnt vmcnt(0)" ::: "memory")

// ---------------- gating: softmax(x @ Wg + bg) -> g [N_TOK][NE] (f32) -----------
__global__ void gate_kernel(const float* __restrict__ x, const float* __restrict__ Wg,
                            const float* __restrict__ bg, float* __restrict__ g) {
    int w = threadIdx.x >> 6, lane = threadIdx.x & 63;
    int n = blockIdx.x * 4 + w;
    const float* xr = x + (size_t)n * DIN;
    float p[NE];
#pragma unroll
    for (int e = 0; e < NE; ++e) p[e] = 0.f;
    for (int i = lane; i < DIN; i += 64) {
        float xv = xr[i];
        const float* wr_ = Wg + i * NE;
#pragma unroll
        for (int e = 0; e < NE; ++e) p[e] = fmaf(xv, wr_[e], p[e]);
    }
#pragma unroll
    for (int off = 32; off > 0; off >>= 1) {
#pragma unroll
        for (int e = 0; e < NE; ++e) p[e] += __shfl_down(p[e], off);
    }
    if (lane == 0) {
        float l2[NE], m = -1e30f;
#pragma unroll
        for (int e = 0; e < NE; ++e) { l2[e] = p[e] + bg[e]; m = fmaxf(m, l2[e]); }
        float s = 0.f;
#pragma unroll
        for (int e = 0; e < NE; ++e) { l2[e] = expf(l2[e] - m); s += l2[e]; }
        float inv = 1.f / s;
#pragma unroll
        for (int e = 0; e < NE; ++e) g[n * NE + e] = l2[e] * inv;
    }
}

// ---------------- x (f32) -> xb (bf16) ------------------------------------------
__global__ void cvt_x_kernel(const float* __restrict__ x, ushort* __restrict__ xb) {
    int idx = blockIdx.x * 256 + threadIdx.x;
    float4 v = ((const float4*)x)[idx];
    ushort4 o = make_ushort4(f2bf(v.x), f2bf(v.y), f2bf(v.z), f2bf(v.w));
    ((ushort4*)xb)[idx] = o;
}

// ---------------- We [8192][1024] f32 -> BT [1024][8192] bf16 (transposed) ------
__global__ void transpose_w_kernel(const float* __restrict__ We, ushort* __restrict__ BT) {
    __shared__ float tile[64][65];
    int kb = blockIdx.x * 64, ob = blockIdx.y * 64;
    int t = threadIdx.x;
#pragma unroll
    for (int ph = 0; ph < 16; ++ph) {
        int idx = ph * 256 + t;
        int r = idx >> 6, c = idx & 63;
        tile[r][c] = We[(size_t)(kb + r) * DOUT + ob + c];
    }
    __syncthreads();
#pragma unroll
    for (int ph = 0; ph < 16; ++ph) {
        int idx = ph * 256 + t;
        int r = idx >> 6, c = idx & 63;
        BT[(size_t)(ob + r) * KTOT + kb + c] = f2bf(tile[c][r]);
    }
}

// ---------------- fused MoE GEMM: ring-4 LDS + frag read-ahead (reg dbuf) --------
// Phase k: {issue 8 ds_reads for frags k+1} || {issue gload group k+3} ->
// lgkmcnt(8) (frags k ready) -> 16 MFMA on frags k -> [fold] -> vmcnt(3)
// (group k+2 landed) -> barrier.  LDS-read burst hides under MFMA burst.
__global__ __launch_bounds__(512, 2) void moe_gemm(
    const ushort* __restrict__ xb,   // [8192][1024] bf16
    const ushort* __restrict__ BT,   // [1024][8192] bf16 (o-major, k-minor)
    const float*  __restrict__ g,    // [8192][8]
    const float*  __restrict__ be,   // [8][1024]
    float*        __restrict__ out)  // [8192][1024]
{
    __shared__ __align__(16) ushort Al[4][BM * 32];   // 64 KB ring
    __shared__ __align__(16) ushort Bl[4][BN * 32];   // 32 KB ring
    __shared__ __align__(16) float  gLds[BM][NE];     //  8 KB

    int bid = blockIdx.x;
    int swz = (bid & 7) * 32 + (bid >> 3);      // XCD row-slab swizzle (proven)
    int colb = swz & 7;
    int rowb = swz >> 3;
    int brow = rowb * BM, bcol = colb * BN;

    int tid = threadIdx.x;
    int w = tid >> 6, lane = tid & 63;
    int wm = w >> 1, wn = w & 1;                 // 4x2 wave grid, 64x64 per wave
    int ro = lane & 15, gq = lane >> 4;
    int jrow = gq * 4;

    // gate probs -> LDS
    float4 gv = ((const float4*)(g + (size_t)brow * NE))[tid];
    ((float4*)&gLds[0][0])[tid] = gv;

    // fragment read offsets (T2-swizzled)
    int offA[4], offB[4];
#pragma unroll
    for (int m = 0; m < 4; ++m) {
        int r = wm * 64 + m * 16 + ro;
        offA[m] = r * 32 + ((gq * 8) ^ ((r & 6) << 2));
    }
#pragma unroll
    for (int n = 0; n < 4; ++n) {
        int c = wn * 64 + n * 16 + ro;
        offB[n] = c * 32 + ((gq * 8) ^ ((c & 6) << 2));
    }

    auto stA = [&](int s, int K) {
#pragma unroll
        for (int L = 0; L < 2; ++L) {
            int chunk = L * 512 + tid;
            int row = chunk >> 2, slot = chunk & 3;
            int ks = (slot * 8) ^ ((row & 6) << 2);
            int ka = (K * 32) & (DIN - 1);
            gload_lds16(xb + (size_t)(brow + row) * DIN + ka + ks,
                        (char*)&Al[s][0] + (size_t)(chunk & ~63) * 16);
        }
    };
    auto stB = [&](int s, int K) {
        int chunk = tid;
        int row = chunk >> 2, slot = chunk & 3;
        int ks = (slot * 8) ^ ((row & 6) << 2);
        gload_lds16(BT + (size_t)(bcol + row) * KTOT + K * 32 + ks,
                    (char*)&Bl[s][0] + (size_t)(chunk & ~63) * 16);
    };

    f32x4 accP[4][4];
    u32   accB[4][4][2];
    short8 fA[2][4], fB[2][4];     // literal-indexed only (reg double-buffer)
#pragma unroll
    for (int m = 0; m < 4; ++m)
#pragma unroll
        for (int n = 0; n < 4; ++n) {
            accP[m][n] = (f32x4){0.f, 0.f, 0.f, 0.f};
            accB[m][n][0] = 0u; accB[m][n][1] = 0u;
        }

    auto fold = [&](int e) {
#pragma unroll
        for (int m = 0; m < 4; ++m) {
            int rbase = wm * 64 + m * 16 + jrow;
            float g0 = gLds[rbase + 0][e], g1 = gLds[rbase + 1][e];
            float g2 = gLds[rbase + 2][e], g3 = gLds[rbase + 3][e];
#pragma unroll
            for (int n = 0; n < 4; ++n) {
                u32 p0 = accB[m][n][0];
                float lo0 = __uint_as_float(p0 << 16)         + g0 * accP[m][n][0];
                float hi0 = __uint_as_float(p0 & 0xffff0000u) + g1 * accP[m][n][1];
                accB[m][n][0] = (u32)f2bf(lo0) | ((u32)f2bf(hi0) << 16);
                u32 p1 = accB[m][n][1];
                float lo1 = __uint_as_float(p1 << 16)         + g2 * accP[m][n][2];
                float hi1 = __uint_as_float(p1 & 0xffff0000u) + g3 * accP[m][n][3];
                accB[m][n][1] = (u32)f2bf(lo1) | ((u32)f2bf(hi1) << 16);
                accP[m][n] = (f32x4){0.f, 0.f, 0.f, 0.f};
            }
        }
    };

#define LD_FRAGS(SET, RBUF) do {                                              \
    const ushort* _As = &Al[RBUF][0];                                         \
    const ushort* _Bs = &Bl[RBUF][0];                                         \
    _Pragma("unroll") for (int _m = 0; _m < 4; ++_m)                          \
        fA[SET][_m] = *(const short8*)(_As + offA[_m]);                       \
    _Pragma("unroll") for (int _n = 0; _n < 4; ++_n)                          \
        fB[SET][_n] = *(const short8*)(_Bs + offB[_n]);                       \
} while (0)

#define DO_MFMA(SET) do {                                                     \
    __builtin_amdgcn_s_setprio(1);                                            \
    _Pragma("unroll") for (int _m = 0; _m < 4; ++_m) {                        \
        accP[_m][0] = __builtin_amdgcn_mfma_f32_16x16x32_bf16(fA[SET][_m], fB[SET][0], accP[_m][0], 0, 0, 0); \
        accP[_m][1] = __builtin_amdgcn_mfma_f32_16x16x32_bf16(fA[SET][_m], fB[SET][1], accP[_m][1], 0, 0, 0); \
        accP[_m][2] = __builtin_amdgcn_mfma_f32_16x16x32_bf16(fA[SET][_m], fB[SET][2], accP[_m][2], 0, 0, 0); \
        accP[_m][3] = __builtin_amdgcn_mfma_f32_16x16x32_bf16(fA[SET][_m], fB[SET][3], accP[_m][3], 0, 0, 0); \
    }                                                                         \
    __builtin_amdgcn_s_setprio(0);                                            \
} while (0)

    // prologue: stage groups 0,1,2; wait groups 0,1; read frags 0 into SET0
    stA(0, 0); stB(0, 0);
    stA(1, 1); stB(1, 1);
    stA(2, 2); stB(2, 2);
    VMCNT3();
    PH_BAR();
    LD_FRAGS(0, 0);

    // main loop: phases 0..251, unrolled x4 so ring/set indices are literals
    for (int it = 0; it < 63; ++it) {
        int k = it * 4;
        // phase k+0: frags in SET0, read-ahead into SET1 from buf1 (group k+1)
        LD_FRAGS(1, 1); stA(3, k + 3); stB(3, k + 3);
        LGKM8(); DO_MFMA(0); VMCNT3(); PH_BAR();
        // phase k+1
        LD_FRAGS(0, 2); stA(0, k + 4); stB(0, k + 4);
        LGKM8(); DO_MFMA(1); VMCNT3(); PH_BAR();
        // phase k+2
        LD_FRAGS(1, 3); stA(1, k + 5); stB(1, k + 5);
        LGKM8(); DO_MFMA(0); VMCNT3(); PH_BAR();
        // phase k+3 (fold experts 0..6 when (k+3) & 31 == 31)
        LD_FRAGS(0, 0); stA(2, k + 6); stB(2, k + 6);
        LGKM8(); DO_MFMA(1);
        if ((it & 7) == 7) fold(it >> 3);
        VMCNT3(); PH_BAR();
    }

    // tail: phases 252..255 (drain)
    LD_FRAGS(1, 1); stA(3, 255); stB(3, 255);
    LGKM8(); DO_MFMA(0); VMCNT3(); PH_BAR();            // phase 252
    LD_FRAGS(0, 2);
    LGKM8(); DO_MFMA(1); VMCNT0(); PH_BAR();            // phase 253
    LD_FRAGS(1, 3);
    LGKM8(); DO_MFMA(0); PH_BAR();                      // phase 254
    LGKM0(); DO_MFMA(1);                                // phase 255 (expert 7 stays in accP)

#undef LD_FRAGS
#undef DO_MFMA

    // epilogue: out = unpack(accB) + g7*accP + sum_e g_e*be_e
#pragma unroll
    for (int m = 0; m < 4; ++m) {
#pragma unroll
        for (int j = 0; j < 4; ++j) {
            int lrow = wm * 64 + m * 16 + jrow + j;
            int grow = brow + lrow;
            float g8[NE];
#pragma unroll
            for (int e = 0; e < NE; ++e) g8[e] = gLds[lrow][e];
#pragma unroll
            for (int n = 0; n < 4; ++n) {
                int col = bcol + wn * 64 + n * 16 + ro;
                float bias = 0.f;
#pragma unroll
                for (int e = 0; e < NE; ++e) bias = fmaf(g8[e], be[e * DOUT + col], bias);
                u32 p = accB[m][n][j >> 1];
                float base = __uint_as_float((j & 1) ? (p & 0xffff0000u) : (p << 16));
                out[(size_t)grow * DOUT + col] = base + g8[7] * accP[m][n][j] + bias;
            }
        }
    }
}

extern "C" void kernel_launch(void* const* d_in, const int* in_sizes, int n_in,
                              void* d_out, int out_size, void* d_ws, size_t ws_size,
                              hipStream_t stream) {
    const float* x  = (const float*)d_in[0];
    const float* We = (const float*)d_in[1];
    const float* be = (const float*)d_in[2];
    const float* Wg = (const float*)d_in[3];
    const float* bg = (const float*)d_in[4];
    float* out = (float*)d_out;

    char* ws = (char*)d_ws;
    float*  gbuf = (float*)ws;                                       // 256 KB
    ushort* xb   = (ushort*)(ws + (size_t)256 * 1024);               // 16 MB
    ushort* BT   = (ushort*)(ws + (size_t)256 * 1024 + (size_t)N_TOK * DIN * 2); // 16 MB

    gate_kernel<<<N_TOK / 4, 256, 0, stream>>>(x, Wg, bg, gbuf);
    cvt_x_kernel<<<(N_TOK * DIN / 4) / 256, 256, 0, stream>>>(x, xb);
    transpose_w_kernel<<<dim3(KTOT / 64, DOUT / 64), 256, 0, stream>>>(We, BT);
    moe_gemm<<<(N_TOK / BM) * (DOUT / BN), 512, 0, stream>>>(xb, BT, gbuf, be, out);
}

// Round 6
// 197.008 us; speedup vs baseline: 1.0036x; 1.0036x over previous
//
#include <hip/hip_runtime.h>
#include <hip/hip_bf16.h>

#define N_TOK 8192
#define DIN   1024
#define DOUT  1024
#define NE    8
#define KTOT  (NE * DIN)          // 8192
#define BM    256
#define BN    128
#define NKH   (KTOT / 32)         // 256 phases (k=32 each)

typedef __attribute__((ext_vector_type(4))) float f32x4;
typedef __attribute__((ext_vector_type(8))) short short8;
typedef unsigned int u32;

__device__ __forceinline__ ushort f2bf(float f) {
    u32 u = __float_as_uint(f);
    u32 r = (u + 0x7fffu + ((u >> 16) & 1u)) >> 16;   // round-to-nearest-even
    return (ushort)r;
}

__device__ __forceinline__ void gload_lds16(const void* gp, void* lp) {
    __builtin_amdgcn_global_load_lds(
        (const __attribute__((address_space(1))) u32*)gp,
        (__attribute__((address_space(3))) u32*)lp, 16, 0, 0);
}

#define PH_BAR()  __builtin_amdgcn_s_barrier()
#define LGKM0()   asm volatile("s_waitcnt lgkmcnt(0)" ::: "memory")
#define LGKM8()   asm volatile("s_waitcnt lgkmcnt(8)" ::: "memory")
#define VMCNT3()  asm volatile("s_waitcnt vmcnt(3)" ::: "memory")
#define VMCNT0()  asm volatile("s_waitcnt vmcnt(0)" ::: "memory")
// rule #18: pin MFMAs below the lgkm wait (inline-asm memory clobber does NOT
// order register-only MFMAs; without this fence the scheduler hoists the MFMA
// burst above the just-issued ds_reads and serializes the two pipes).
#define SBAR0()   __builtin_amdgcn_sched_barrier(0)

// ---------------- gating: softmax(x @ Wg + bg) -> g [N_TOK][NE] (f32) -----------
__global__ void gate_kernel(const float* __restrict__ x, const float* __restrict__ Wg,
                            const float* __restrict__ bg, float* __restrict__ g) {
    int w = threadIdx.x >> 6, lane = threadIdx.x & 63;
    int n = blockIdx.x * 4 + w;
    const float* xr = x + (size_t)n * DIN;
    float p[NE];
#pragma unroll
    for (int e = 0; e < NE; ++e) p[e] = 0.f;
    for (int i = lane; i < DIN; i += 64) {
        float xv = xr[i];
        const float* wr_ = Wg + i * NE;
#pragma unroll
        for (int e = 0; e < NE; ++e) p[e] = fmaf(xv, wr_[e], p[e]);
    }
#pragma unroll
    for (int off = 32; off > 0; off >>= 1) {
#pragma unroll
        for (int e = 0; e < NE; ++e) p[e] += __shfl_down(p[e], off);
    }
    if (lane == 0) {
        float l2[NE], m = -1e30f;
#pragma unroll
        for (int e = 0; e < NE; ++e) { l2[e] = p[e] + bg[e]; m = fmaxf(m, l2[e]); }
        float s = 0.f;
#pragma unroll
        for (int e = 0; e < NE; ++e) { l2[e] = expf(l2[e] - m); s += l2[e]; }
        float inv = 1.f / s;
#pragma unroll
        for (int e = 0; e < NE; ++e) g[n * NE + e] = l2[e] * inv;
    }
}

// ---------------- x (f32) -> xb (bf16) ------------------------------------------
__global__ void cvt_x_kernel(const float* __restrict__ x, ushort* __restrict__ xb) {
    int idx = blockIdx.x * 256 + threadIdx.x;
    float4 v = ((const float4*)x)[idx];
    ushort4 o = make_ushort4(f2bf(v.x), f2bf(v.y), f2bf(v.z), f2bf(v.w));
    ((ushort4*)xb)[idx] = o;
}

// ---------------- We [8192][1024] f32 -> BT [1024][8192] bf16 (transposed) ------
__global__ void transpose_w_kernel(const float* __restrict__ We, ushort* __restrict__ BT) {
    __shared__ float tile[64][65];
    int kb = blockIdx.x * 64, ob = blockIdx.y * 64;
    int t = threadIdx.x;
#pragma unroll
    for (int ph = 0; ph < 16; ++ph) {
        int idx = ph * 256 + t;
        int r = idx >> 6, c = idx & 63;
        tile[r][c] = We[(size_t)(kb + r) * DOUT + ob + c];
    }
    __syncthreads();
#pragma unroll
    for (int ph = 0; ph < 16; ++ph) {
        int idx = ph * 256 + t;
        int r = idx >> 6, c = idx & 63;
        BT[(size_t)(ob + r) * KTOT + kb + c] = f2bf(tile[c][r]);
    }
}

// ---------------- fused MoE GEMM: ring-4 LDS + frag read-ahead + sched fence -----
// Phase k: {8 ds_reads for frags k+1} || {gload group k+3} -> lgkmcnt(8) ->
// sched_barrier(0) -> 16 MFMA on frags k -> [fold] -> vmcnt(3) -> barrier.
__global__ __launch_bounds__(512, 2) void moe_gemm(
    const ushort* __restrict__ xb,   // [8192][1024] bf16
    const ushort* __restrict__ BT,   // [1024][8192] bf16 (o-major, k-minor)
    const float*  __restrict__ g,    // [8192][8]
    const float*  __restrict__ be,   // [8][1024]
    float*        __restrict__ out)  // [8192][1024]
{
    __shared__ __align__(16) ushort Al[4][BM * 32];   // 64 KB ring
    __shared__ __align__(16) ushort Bl[4][BN * 32];   // 32 KB ring
    __shared__ __align__(16) float  gLds[BM][NE];     //  8 KB

    int bid = blockIdx.x;
    int swz = (bid & 7) * 32 + (bid >> 3);      // XCD row-slab swizzle (proven)
    int colb = swz & 7;
    int rowb = swz >> 3;
    int brow = rowb * BM, bcol = colb * BN;

    int tid = threadIdx.x;
    int w = tid >> 6, lane = tid & 63;
    int wm = w >> 1, wn = w & 1;                 // 4x2 wave grid, 64x64 per wave
    int ro = lane & 15, gq = lane >> 4;
    int jrow = gq * 4;

    // gate probs -> LDS
    float4 gv = ((const float4*)(g + (size_t)brow * NE))[tid];
    ((float4*)&gLds[0][0])[tid] = gv;

    // fragment read offsets (T2-swizzled)
    int offA[4], offB[4];
#pragma unroll
    for (int m = 0; m < 4; ++m) {
        int r = wm * 64 + m * 16 + ro;
        offA[m] = r * 32 + ((gq * 8) ^ ((r & 6) << 2));
    }
#pragma unroll
    for (int n = 0; n < 4; ++n) {
        int c = wn * 64 + n * 16 + ro;
        offB[n] = c * 32 + ((gq * 8) ^ ((c & 6) << 2));
    }

    auto stA = [&](int s, int K) {
#pragma unroll
        for (int L = 0; L < 2; ++L) {
            int chunk = L * 512 + tid;
            int row = chunk >> 2, slot = chunk & 3;
            int ks = (slot * 8) ^ ((row & 6) << 2);
            int ka = (K * 32) & (DIN - 1);
            gload_lds16(xb + (size_t)(brow + row) * DIN + ka + ks,
                        (char*)&Al[s][0] + (size_t)(chunk & ~63) * 16);
        }
    };
    auto stB = [&](int s, int K) {
        int chunk = tid;
        int row = chunk >> 2, slot = chunk & 3;
        int ks = (slot * 8) ^ ((row & 6) << 2);
        gload_lds16(BT + (size_t)(bcol + row) * KTOT + K * 32 + ks,
                    (char*)&Bl[s][0] + (size_t)(chunk & ~63) * 16);
    };

    f32x4 accP[4][4];
    u32   accB[4][4][2];
    short8 fA[2][4], fB[2][4];     // literal-indexed only (reg double-buffer)
#pragma unroll
    for (int m = 0; m < 4; ++m)
#pragma unroll
        for (int n = 0; n < 4; ++n) {
            accP[m][n] = (f32x4){0.f, 0.f, 0.f, 0.f};
            accB[m][n][0] = 0u; accB[m][n][1] = 0u;
        }

    auto fold = [&](int e) {
#pragma unroll
        for (int m = 0; m < 4; ++m) {
            int rbase = wm * 64 + m * 16 + jrow;
            float g0 = gLds[rbase + 0][e], g1 = gLds[rbase + 1][e];
            float g2 = gLds[rbase + 2][e], g3 = gLds[rbase + 3][e];
#pragma unroll
            for (int n = 0; n < 4; ++n) {
                u32 p0 = accB[m][n][0];
                float lo0 = __uint_as_float(p0 << 16)         + g0 * accP[m][n][0];
                float hi0 = __uint_as_float(p0 & 0xffff0000u) + g1 * accP[m][n][1];
                accB[m][n][0] = (u32)f2bf(lo0) | ((u32)f2bf(hi0) << 16);
                u32 p1 = accB[m][n][1];
                float lo1 = __uint_as_float(p1 << 16)         + g2 * accP[m][n][2];
                float hi1 = __uint_as_float(p1 & 0xffff0000u) + g3 * accP[m][n][3];
                accB[m][n][1] = (u32)f2bf(lo1) | ((u32)f2bf(hi1) << 16);
                accP[m][n] = (f32x4){0.f, 0.f, 0.f, 0.f};
            }
        }
    };

#define LD_FRAGS(SET, RBUF) do {                                              \
    const ushort* _As = &Al[RBUF][0];                                         \
    const ushort* _Bs = &Bl[RBUF][0];                                         \
    _Pragma("unroll") for (int _m = 0; _m < 4; ++_m)                          \
        fA[SET][_m] = *(const short8*)(_As + offA[_m]);                       \
    _Pragma("unroll") for (int _n = 0; _n < 4; ++_n)                          \
        fB[SET][_n] = *(const short8*)(_Bs + offB[_n]);                       \
} while (0)

#define DO_MFMA(SET) do {                                                     \
    __builtin_amdgcn_s_setprio(1);                                            \
    _Pragma("unroll") for (int _m = 0; _m < 4; ++_m) {                        \
        accP[_m][0] = __builtin_amdgcn_mfma_f32_16x16x32_bf16(fA[SET][_m], fB[SET][0], accP[_m][0], 0, 0, 0); \
        accP[_m][1] = __builtin_amdgcn_mfma_f32_16x16x32_bf16(fA[SET][_m], fB[SET][1], accP[_m][1], 0, 0, 0); \
        accP[_m][2] = __builtin_amdgcn_mfma_f32_16x16x32_bf16(fA[SET][_m], fB[SET][2], accP[_m][2], 0, 0, 0); \
        accP[_m][3] = __builtin_amdgcn_mfma_f32_16x16x32_bf16(fA[SET][_m], fB[SET][3], accP[_m][3], 0, 0, 0); \
    }                                                                         \
    __builtin_amdgcn_s_setprio(0);                                            \
} while (0)

    // prologue: stage groups 0,1,2; wait groups 0,1; read frags 0 into SET0
    stA(0, 0); stB(0, 0);
    stA(1, 1); stB(1, 1);
    stA(2, 2); stB(2, 2);
    VMCNT3();
    PH_BAR();
    LD_FRAGS(0, 0);

    // main loop: phases 0..251, unrolled x4 so ring/set indices are literals
    for (int it = 0; it < 63; ++it) {
        int k = it * 4;
        // phase k+0: frags in SET0, read-ahead into SET1 from buf1 (group k+1)
        LD_FRAGS(1, 1); stA(3, k + 3); stB(3, k + 3);
        LGKM8(); SBAR0(); DO_MFMA(0); VMCNT3(); PH_BAR();
        // phase k+1
        LD_FRAGS(0, 2); stA(0, k + 4); stB(0, k + 4);
        LGKM8(); SBAR0(); DO_MFMA(1); VMCNT3(); PH_BAR();
        // phase k+2
        LD_FRAGS(1, 3); stA(1, k + 5); stB(1, k + 5);
        LGKM8(); SBAR0(); DO_MFMA(0); VMCNT3(); PH_BAR();
        // phase k+3 (fold experts 0..6 when (k+3) & 31 == 31)
        LD_FRAGS(0, 0); stA(2, k + 6); stB(2, k + 6);
        LGKM8(); SBAR0(); DO_MFMA(1);
        if ((it & 7) == 7) fold(it >> 3);
        VMCNT3(); PH_BAR();
    }

    // tail: phases 252..255 (drain)
    LD_FRAGS(1, 1); stA(3, 255); stB(3, 255);
    LGKM8(); SBAR0(); DO_MFMA(0); VMCNT3(); PH_BAR();   // phase 252
    LD_FRAGS(0, 2);
    LGKM8(); SBAR0(); DO_MFMA(1); VMCNT0(); PH_BAR();   // phase 253
    LD_FRAGS(1, 3);
    LGKM8(); SBAR0(); DO_MFMA(0); PH_BAR();             // phase 254
    LGKM0(); SBAR0(); DO_MFMA(1);                       // phase 255 (expert 7 in accP)

#undef LD_FRAGS
#undef DO_MFMA

    // epilogue: out = unpack(accB) + g7*accP + sum_e g_e*be_e
#pragma unroll
    for (int m = 0; m < 4; ++m) {
#pragma unroll
        for (int j = 0; j < 4; ++j) {
            int lrow = wm * 64 + m * 16 + jrow + j;
            int grow = brow + lrow;
            float g8[NE];
#pragma unroll
            for (int e = 0; e < NE; ++e) g8[e] = gLds[lrow][e];
#pragma unroll
            for (int n = 0; n < 4; ++n) {
                int col = bcol + wn * 64 + n * 16 + ro;
                float bias = 0.f;
#pragma unroll
                for (int e = 0; e < NE; ++e) bias = fmaf(g8[e], be[e * DOUT + col], bias);
                u32 p = accB[m][n][j >> 1];
                float base = __uint_as_float((j & 1) ? (p & 0xffff0000u) : (p << 16));
                out[(size_t)grow * DOUT + col] = base + g8[7] * accP[m][n][j] + bias;
            }
        }
    }
}

extern "C" void kernel_launch(void* const* d_in, const int* in_sizes, int n_in,
                              void* d_out, int out_size, void* d_ws, size_t ws_size,
                              hipStream_t stream) {
    const float* x  = (const float*)d_in[0];
    const float* We = (const float*)d_in[1];
    const float* be = (const float*)d_in[2];
    const float* Wg = (const float*)d_in[3];
    const float* bg = (const float*)d_in[4];
    float* out = (float*)d_out;

    char* ws = (char*)d_ws;
    float*  gbuf = (float*)ws;                                       // 256 KB
    ushort* xb   = (ushort*)(ws + (size_t)256 * 1024);               // 16 MB
    ushort* BT   = (ushort*)(ws + (size_t)256 * 1024 + (size_t)N_TOK * DIN * 2); // 16 MB

    gate_kernel<<<N_TOK / 4, 256, 0, stream>>>(x, Wg, bg, gbuf);
    cvt_x_kernel<<<(N_TOK * DIN / 4) / 256, 256, 0, stream>>>(x, xb);
    transpose_w_kernel<<<dim3(KTOT / 64, DOUT / 64), 256, 0, stream>>>(We, BT);
    moe_gemm<<<(N_TOK / BM) * (DOUT / BN), 512, 0, stream>>>(xb, BT, gbuf, be, out);
}